// Round 6
// baseline (7894.544 us; speedup 1.0000x reference)
//
#include <hip/hip_runtime.h>

#define BB 64
#define NN 128
#define DD 512
#define NBLK 128
#define NTHR 512
#define GCOLS 24
#define WCS 2056    // u16 per combined-weight col: [W0h 512|W1h 512|W0l 512|W1l 512|pad 8]
#define BCS2 10240  // f32/batch: [0,512) M1 | [512,3584) gates | [3584,9728) x double | [9728,10240) M2

typedef unsigned short u16;
typedef unsigned int u32;
typedef unsigned long long u64;
typedef __attribute__((ext_vector_type(8))) __bf16 bf16x8;
typedef __attribute__((ext_vector_type(4))) float f32x4;

#define MFMA16(a, b, c) __builtin_amdgcn_mfma_f32_16x16x32_bf16((a), (b), (c), 0, 0, 0)

__device__ __forceinline__ float b2f(u16 u) {
    union { u32 i; float f; } c; c.i = ((u32)u) << 16; return c.f;
}
__device__ __forceinline__ u16 f2b(float f) {
    union { float f; u32 i; } c; c.f = f;
    return (u16)((c.i + 0x7FFFu + ((c.i >> 16) & 1u)) >> 16);
}
__device__ __forceinline__ float sigm(float x) { return 1.f / (1.f + __expf(-x)); }
__device__ __forceinline__ float tanh_(float x) {
    x = fminf(fmaxf(x, -15.f), 15.f);
    float e = __expf(2.f * x);
    return (e - 1.f) / (e + 1.f);
}

// ---- L2-bypass (sc0 sc1) accessors via agent-scope relaxed atomics ----
__device__ __forceinline__ float ldf_cv(const float* p) {
    return __hip_atomic_load(p, __ATOMIC_RELAXED, __HIP_MEMORY_SCOPE_AGENT);
}
__device__ __forceinline__ void stf_wt(float* p, float v) {
    __hip_atomic_store(p, v, __ATOMIC_RELAXED, __HIP_MEMORY_SCOPE_AGENT);
}
__device__ __forceinline__ void stu32_wt(u32* p, u32 v) {
    __hip_atomic_store(p, v, __ATOMIC_RELAXED, __HIP_MEMORY_SCOPE_AGENT);
}
__device__ __forceinline__ bf16x8 ld8h_cv(const u16* p) {   // 16B fresh load as 2x u64
    union { u64 q[2]; bf16x8 v; } u;
    u.q[0] = __hip_atomic_load((const u64*)p, __ATOMIC_RELAXED, __HIP_MEMORY_SCOPE_AGENT);
    u.q[1] = __hip_atomic_load((const u64*)(p + 4), __ATOMIC_RELAXED, __HIP_MEMORY_SCOPE_AGENT);
    return u.v;
}

// heavy barrier (acq/rel): used ONCE after the prologue to publish cacheable data
__device__ __forceinline__ void gbar_heavy(int* sync, int gen, int blk) {
    __syncthreads();
    int* epoch = sync;
    if (blk == 0) {
        const int t = threadIdx.x;
        int done = (t == 0 || t >= NBLK) ? 1 : 0;
        int* myarr = sync + 256 + t * 16;
        int it = 0;
        for (;;) {
            if (!done) {
                int v = ((it & 15) == 15)
                    ? __hip_atomic_load(myarr, __ATOMIC_ACQUIRE, __HIP_MEMORY_SCOPE_AGENT)
                    : __hip_atomic_load(myarr, __ATOMIC_RELAXED, __HIP_MEMORY_SCOPE_AGENT);
                done = (v >= gen);
            }
            ++it;
            if (__syncthreads_and(done)) break;
            __builtin_amdgcn_s_sleep(1);
        }
        if (t == 0) {
            (void)__hip_atomic_load(sync + 256 + 16, __ATOMIC_ACQUIRE, __HIP_MEMORY_SCOPE_AGENT);
            __hip_atomic_store(epoch, gen, __ATOMIC_RELEASE, __HIP_MEMORY_SCOPE_AGENT);
        }
        __syncthreads();
    } else {
        if (threadIdx.x == 0) {
            __hip_atomic_store(sync + 256 + blk * 16, gen, __ATOMIC_RELEASE, __HIP_MEMORY_SCOPE_AGENT);
            int it = 0;
            for (;;) {
                int v = ((it & 15) == 15)
                    ? __hip_atomic_load(epoch, __ATOMIC_ACQUIRE, __HIP_MEMORY_SCOPE_AGENT)
                    : __hip_atomic_load(epoch, __ATOMIC_RELAXED, __HIP_MEMORY_SCOPE_AGENT);
                ++it;
                if (v >= gen) break;
                __builtin_amdgcn_s_sleep(1);
            }
            (void)__hip_atomic_load(epoch, __ATOMIC_ACQUIRE, __HIP_MEMORY_SCOPE_AGENT);
        }
        __syncthreads();
    }
}

// light barrier: relaxed flags only, no wbl2/inv. Rare ACQUIRE as hang insurance.
__device__ __forceinline__ void gbar_light(int* sync, int gen, int blk) {
    __syncthreads();   // drains vmem (data stores are in IF$ before flag store)
    int* epoch = sync;
    if (blk == 0) {
        const int t = threadIdx.x;
        int done = (t == 0 || t >= NBLK) ? 1 : 0;
        int* myarr = sync + 256 + t * 16;
        int it = 0;
        for (;;) {
            if (!done) {
                int v = ((it & 63) == 63)
                    ? __hip_atomic_load(myarr, __ATOMIC_ACQUIRE, __HIP_MEMORY_SCOPE_AGENT)
                    : __hip_atomic_load(myarr, __ATOMIC_RELAXED, __HIP_MEMORY_SCOPE_AGENT);
                done = (v >= gen);
            }
            ++it;
            if (__syncthreads_and(done)) break;
            __builtin_amdgcn_s_sleep(1);
        }
        if (t == 0)
            __hip_atomic_store(epoch, gen, __ATOMIC_RELAXED, __HIP_MEMORY_SCOPE_AGENT);
        __syncthreads();
    } else {
        if (threadIdx.x == 0) {
            __hip_atomic_store(sync + 256 + blk * 16, gen, __ATOMIC_RELAXED, __HIP_MEMORY_SCOPE_AGENT);
            int it = 0;
            for (;;) {
                int v = ((it & 63) == 63)
                    ? __hip_atomic_load(epoch, __ATOMIC_ACQUIRE, __HIP_MEMORY_SCOPE_AGENT)
                    : __hip_atomic_load(epoch, __ATOMIC_RELAXED, __HIP_MEMORY_SCOPE_AGENT);
                ++it;
                if (v >= gen) break;
                __builtin_amdgcn_s_sleep(1);
            }
        }
        __syncthreads();
    }
}

// gates GEMM: 64 x 24 slice, K=1024 ([u0;u1]) hi/lo 3-term. A=ublob (bypass), W=LDS.
__device__ __forceinline__ void gates_task(
    const u16* __restrict__ ublob, const u16* s_wc, const float* s_gb,
    float* __restrict__ bc, int blk, int task, int lr, int lq)
{
    const int ct = task & 1, rt = task >> 1;
    const int cc = ct * 8 + lr;
    const int col = blk * GCOLS + cc;
    const u16* wcol = s_wc + cc * WCS;
    const u16* arow = ublob + (size_t)(rt * 16 + lr) * 2048;
    f32x4 acc = {0.f, 0.f, 0.f, 0.f};
    #pragma unroll 4
    for (int c = 0; c < 16; ++c) {
        int kk = c * 32 + lq * 8;
        bf16x8 ah = ld8h_cv(arow + kk);
        bf16x8 al = ld8h_cv(arow + 512 + kk);
        bf16x8 wh = *(const bf16x8*)(wcol + kk);
        bf16x8 wl = *(const bf16x8*)(wcol + 1024 + kk);
        acc = MFMA16(ah, wh, acc); acc = MFMA16(al, wh, acc); acc = MFMA16(ah, wl, acc);
    }
    #pragma unroll 4
    for (int c = 0; c < 16; ++c) {
        int kk = c * 32 + lq * 8;
        bf16x8 ah = ld8h_cv(arow + 1024 + kk);
        bf16x8 al = ld8h_cv(arow + 1536 + kk);
        bf16x8 wh = *(const bf16x8*)(wcol + 512 + kk);
        bf16x8 wl = *(const bf16x8*)(wcol + 1536 + kk);
        acc = MFMA16(ah, wh, acc); acc = MFMA16(al, wh, acc); acc = MFMA16(ah, wl, acc);
    }
    float bias = s_gb[cc];
    #pragma unroll
    for (int r = 0; r < 4; ++r)
        stf_wt(bc + (size_t)(rt * 16 + lq * 4 + r) * BCS2 + 512 + col, acc[r] + bias);
}

// M half-GEMM: part 0 = u0@Wr0 -> M1, part 1 = u1@Wr1 -> M2. W from global (cached).
__device__ __forceinline__ void m_half(
    const u16* __restrict__ ublob, const u16* __restrict__ WrB,
    float* __restrict__ bc, int blk, int part, int lr, int lq)
{
    const int ct = blk >> 2, rt = blk & 3;
    const int col = ct * 16 + lr;
    const u16* wcol = WrB + (size_t)col * 2048 + part * 1024;
    const u16* arow = ublob + (size_t)(rt * 16 + lr) * 2048 + part * 1024;
    f32x4 acc = {0.f, 0.f, 0.f, 0.f};
    #pragma unroll 4
    for (int c = 0; c < 16; ++c) {
        int kk = c * 32 + lq * 8;
        bf16x8 ah = ld8h_cv(arow + kk);
        bf16x8 al = ld8h_cv(arow + 512 + kk);
        bf16x8 wh = *(const bf16x8*)(wcol + kk);
        bf16x8 wl = *(const bf16x8*)(wcol + 512 + kk);
        acc = MFMA16(ah, wh, acc); acc = MFMA16(al, wh, acc); acc = MFMA16(ah, wl, acc);
    }
    const int mo = part ? 9728 : 0;
    #pragma unroll
    for (int r = 0; r < 4; ++r)
        stf_wt(bc + (size_t)(rt * 16 + lq * 4 + r) * BCS2 + mo + col, acc[r]);
}

// x-gates tile (i, parity): upper blocks, cols = ub*48 + ct*16 + lr. A,W cached normal loads.
__device__ __forceinline__ void x_tile(
    int i, int par, int ub, int ct, int rt,
    const u16* __restrict__ featblob, const u16* __restrict__ WxB,
    const float* __restrict__ bi_c, const float* __restrict__ bh_p,
    float* __restrict__ bc, int lr, int lq)
{
    const int col = ub * 48 + ct * 16 + lr;
    const u16* arow = featblob + (size_t)(i * 64 + rt * 16 + lr) * 1024;
    const u16* wcol = WxB + (size_t)col * 1024;
    f32x4 acc = {0.f, 0.f, 0.f, 0.f};
    #pragma unroll 4
    for (int c = 0; c < 16; ++c) {
        int kk = c * 32 + lq * 8;
        bf16x8 ah = *(const bf16x8*)(arow + kk);
        bf16x8 al = *(const bf16x8*)(arow + 512 + kk);
        bf16x8 wh = *(const bf16x8*)(wcol + kk);
        bf16x8 wl = *(const bf16x8*)(wcol + 512 + kk);
        acc = MFMA16(ah, wh, acc); acc = MFMA16(al, wh, acc); acc = MFMA16(ah, wl, acc);
    }
    float bias = (col < 1536) ? bi_c[col] : bh_p[col - 1536];
    const int xoff = 3584 + par * 3072;
    #pragma unroll
    for (int r = 0; r < 4; ++r)
        stf_wt(bc + (size_t)(rt * 16 + lq * 4 + r) * BCS2 + xoff + col, acc[r] + bias);
}

// GRU-combine for row j>=1 (bc via bypass loads)
__device__ __forceinline__ float ew_compute(
    const float* __restrict__ bcb, const float* __restrict__ feat, int b, int j, int t)
{
    const int xo = 3584 + (j & 1) * 3072;
    float Mv  = ldf_cv(bcb + t) + ldf_cv(bcb + 9728 + t);
    float hr  = ldf_cv(bcb + 512 + t), hz = ldf_cv(bcb + 1024 + t), hn = ldf_cv(bcb + 1536 + t);
    float gir = ldf_cv(bcb + 2048 + t), giz = ldf_cv(bcb + 2560 + t), gin = ldf_cv(bcb + 3072 + t);
    float ir  = ldf_cv(bcb + xo + t), iz = ldf_cv(bcb + xo + 512 + t), inn = ldf_cv(bcb + xo + 1024 + t);
    float ghr = ldf_cv(bcb + xo + 1536 + t), ghz = ldf_cv(bcb + xo + 2048 + t), ghn = ldf_cv(bcb + xo + 2560 + t);
    float x = feat[(size_t)(b * NN + j) * DD + t];
    float r = sigm(ir + hr), z = sigm(iz + hz);
    float C = (1.f - z) * tanh_(inn + r * hn) + z * Mv;
    float r2 = sigm(gir + ghr), z2 = sigm(giz + ghz);
    float P = (1.f - z2) * tanh_(gin + r2 * ghn) + z2 * x;
    return C + P;
}

__global__ __launch_bounds__(NTHR) void grn_kernel(
    const float* __restrict__ feat, const float* __restrict__ Wi_c, const float* __restrict__ Wh_c,
    const float* __restrict__ bi_c, const float* __restrict__ bh_c,
    const float* __restrict__ Wi_p, const float* __restrict__ Wh_p,
    const float* __restrict__ bi_p, const float* __restrict__ bh_p,
    const float* __restrict__ lin_w, const float* __restrict__ lin_b,
    const float* __restrict__ Wr0, const float* __restrict__ Wr1,
    const int* __restrict__ adj, const int* __restrict__ smask,
    float* __restrict__ out,
    float* __restrict__ H, float* __restrict__ q, u16* __restrict__ ublob,
    u16* __restrict__ featblob, float* __restrict__ bc, u16* __restrict__ WrB,
    u16* __restrict__ WxB, int* __restrict__ sync)
{
    const int t = threadIdx.x, blk = blockIdx.x;
    const int lane = t & 63, wv = t >> 6;
    const int lr = lane & 15, lq = lane >> 4;
    int gen = 0;

    __shared__ u16 s_wc[GCOLS * WCS];            // 98688 B, persistent combined weights
    __shared__ float s_stage[DD * GCOLS / 2 * 2]; // 49152 B, prologue Wg staging only
    __shared__ float s_red[NTHR];
    __shared__ float s_red2[NTHR];
    __shared__ float s_hk[NN];
    __shared__ float s_q[NN];
    __shared__ float s_w[NN];
    __shared__ float s_ws[NN];
    __shared__ float s_gb[GCOLS];

    const float wkreg = lin_w[DD + t];

    // ================= Ph0: prologue (all normal stores; heavy barrier publishes) ==========
    for (int rr = 0; rr < 64; ++rr) {          // featblob[(n*64+b)] = hi/lo feat[b,n,:]
        int gr = blk * 64 + rr;
        int bb_ = gr >> 7, nn_ = gr & 127;
        float x = feat[(size_t)gr * DD + t];
        u16 h = f2b(x);
        u16* dst = featblob + (size_t)(nn_ * 64 + bb_) * 1024;
        dst[t] = h;
        dst[512 + t] = f2b(x - b2f(h));
    }
    for (int cc = 0; cc < 4; ++cc) {           // WrB: 512 cols x [W0h|W0l|W1h|W1l]
        int c = blk * 4 + cc;
        float w0 = Wr0[(size_t)c * DD + t], w1 = Wr1[(size_t)c * DD + t];
        u16 h0 = f2b(w0), h1 = f2b(w1);
        u16* dst = WrB + (size_t)c * 2048;
        dst[t] = h0; dst[512 + t] = f2b(w0 - b2f(h0));
        dst[1024 + t] = h1; dst[1536 + t] = f2b(w1 - b2f(h1));
    }
    for (int cc = 0; cc < GCOLS; ++cc) {       // WxB: 3072 cols x [hi|lo]
        int c = blk * GCOLS + cc;
        const float* src = (c < 1536) ? (Wi_c + (size_t)c * DD) : (Wh_p + (size_t)(c - 1536) * DD);
        float w = src[t];
        u16 h = f2b(w);
        WxB[(size_t)c * 1024 + t] = h;
        WxB[(size_t)c * 1024 + 512 + t] = f2b(w - b2f(h));
    }
    {                                          // q[b,n] = feat.wq + lin_b
        float linb = lin_b[0];
        float wqf[8];
        #pragma unroll
        for (int jj = 0; jj < 8; ++jj) wqf[jj] = lin_w[lane * 8 + jj];
        for (int rr = 0; rr < 8; ++rr) {
            int row = blk * 64 + wv * 8 + rr;
            const float* fp = feat + (size_t)row * DD + lane * 8;
            float p = 0.f;
            #pragma unroll
            for (int jj = 0; jj < 8; ++jj) p += fp[jj] * wqf[jj];
            #pragma unroll
            for (int off = 32; off; off >>= 1) p += __shfl_down(p, off, 64);
            if (lane == 0) q[row] = p + linb;
        }
    }
    {                                          // stage Wg rows, build Wcomb into s_wc
        int jg0 = blk * GCOLS;
        for (int cc = 0; cc < GCOLS; ++cc) {
            int jg = jg0 + cc;
            const float* src = (jg < 1536) ? (Wh_c + (size_t)jg * DD) : (Wi_p + (size_t)(jg - 1536) * DD);
            s_stage[t * GCOLS + cc] = src[t];
        }
        if (t < GCOLS) {
            int jg = jg0 + t;
            s_gb[t] = (jg < 1536) ? bh_c[jg] : bi_p[jg - 1536];
        }
        __syncthreads();
        float acc0[GCOLS], acc1[GCOLS];
        #pragma unroll
        for (int cc = 0; cc < GCOLS; ++cc) { acc0[cc] = 0.f; acc1[cc] = 0.f; }
        for (int j = 0; j < DD; ++j) {
            float wr0 = Wr0[(size_t)j * DD + t];
            float wr1 = Wr1[(size_t)j * DD + t];
            const float* g = s_stage + j * GCOLS;
            #pragma unroll
            for (int cc = 0; cc < GCOLS; ++cc) {
                float gv = g[cc];
                acc0[cc] += wr0 * gv;
                acc1[cc] += wr1 * gv;
            }
        }
        __syncthreads();
        #pragma unroll
        for (int cc = 0; cc < GCOLS; ++cc) {
            u16 h0 = f2b(acc0[cc]);
            s_wc[cc * WCS + t] = h0;
            s_wc[cc * WCS + 1024 + t] = f2b(acc0[cc] - b2f(h0));
            u16 h1 = f2b(acc1[cc]);
            s_wc[cc * WCS + 512 + t] = h1;
            s_wc[cc * WCS + 1536 + t] = f2b(acc1[cc] - b2f(h1));
        }
    }
    gbar_heavy(sync, ++gen, blk);

    // ================= Ph0x: x-gates row 0 (upper blocks); s_q load (lower) =================
    if (blk >= BB) {
        int ub = blk - BB;
        #pragma unroll
        for (int pass = 0; pass < 2; ++pass) {
            int tk = wv + pass * 8;
            if (tk < 12) x_tile(0, 0, ub, tk >> 2, tk & 3, featblob, WxB, bi_c, bh_p, bc, lr, lq);
        }
    } else if (t < NN) {
        s_q[t] = q[blk * NN + t];
    }
    gbar_light(sync, ++gen, blk);

    // ================= Ph1: row 0 init =================
    if (blk < BB) {
        const float* bcb = bc + (size_t)blk * BCS2;
        float ir = ldf_cv(bcb + 3584 + t), iz = ldf_cv(bcb + 4096 + t), inn = ldf_cv(bcb + 4608 + t);
        float r = sigm(ir + bh_c[t]), z = sigm(iz + bh_c[512 + t]);
        float C = (1.f - z) * tanh_(inn + r * bh_c[1024 + t]);
        float ghr = ldf_cv(bcb + 5120 + t), ghz = ldf_cv(bcb + 5632 + t), ghn = ldf_cv(bcb + 6144 + t);
        float r2 = sigm(bi_p[t] + ghr), z2 = sigm(bi_p[512 + t] + ghz);
        float n2 = tanh_(bi_p[1024 + t] + r2 * ghn);
        float x = feat[(size_t)(blk * NN) * DD + t];
        float P = (1.f - z2) * n2 + z2 * x;
        float Hv = C + P;
        H[(size_t)(blk * NN) * DD + t] = Hv;
        out[(size_t)(blk * NN) * DD + t] = Hv;
        s_red[t] = Hv * wkreg;
        __syncthreads();
        if (wv == 0) {
            float p = 0.f;
            #pragma unroll
            for (int jj = 0; jj < 8; ++jj) p += s_red[lane + 64 * jj];
            #pragma unroll
            for (int off = 32; off; off >>= 1) p += __shfl_down(p, off, 64);
            if (lane == 0) s_hk[0] = p;
        }
    }
    gbar_light(sync, ++gen, blk);

    // ================= main scan =================
    for (int i = 1; i < NN; ++i) {
        // ---- PhA: lower = finish row i-1 + softmax + H-scan; upper = x-gates row i ----
        if (blk < BB) {
            int va0 = 0, va1 = 0, vs0 = 0, vs1 = 0;
            float qv = 0.f;
            if (wv == 0) {
                const int* ar_ = adj + (size_t)(blk * NN + i) * NN;
                const int* sr_ = smask + (size_t)(blk * NN + i) * NN;
                va0 = ar_[lane]; va1 = ar_[lane + 64];
                vs0 = sr_[lane]; vs1 = sr_[lane + 64];
                qv = s_q[i];
            }
            if (i >= 2) {
                float Hv = ew_compute(bc + (size_t)blk * BCS2, feat, blk, i - 1, t);
                H[(size_t)(blk * NN + i - 1) * DD + t] = Hv;
                out[(size_t)(blk * NN + i - 1) * DD + t] = Hv;
                s_red[t] = Hv * wkreg;
            }
            __syncthreads();
            if (wv == 0) {
                if (i >= 2) {
                    float p = 0.f;
                    #pragma unroll
                    for (int jj = 0; jj < 8; ++jj) p += s_red[lane + 64 * jj];
                    #pragma unroll
                    for (int off = 32; off; off >>= 1) p += __shfl_down(p, off, 64);
                    if (lane == 0) s_hk[i - 1] = p;
                }
                int n2i = lane + 64;
                float a0 = (lane < i && va0 != 0) ? (qv + s_hk[lane]) : -1e30f;
                float a1 = (n2i < i && va1 != 0) ? (qv + s_hk[n2i]) : -1e30f;
                float m = fmaxf(a0, a1);
                #pragma unroll
                for (int off = 32; off; off >>= 1) m = fmaxf(m, __shfl_xor(m, off, 64));
                float e0 = (a0 > -1e29f) ? __expf(a0 - m) : 0.f;
                float e1 = (a1 > -1e29f) ? __expf(a1 - m) : 0.f;
                float ss = e0 + e1;
                #pragma unroll
                for (int off = 32; off; off >>= 1) ss += __shfl_xor(ss, off, 64);
                float inv = 1.f / ss;
                float w0 = e0 * inv, w1 = e1 * inv;
                s_w[lane] = w0; s_w[n2i] = w1;
                s_ws[lane] = w0 * (float)vs0;
                s_ws[n2i] = w1 * (float)vs1;
            }
            __syncthreads();
            // scalar H-scan (thread = dim), L2-resident H, no LDS atomics
            {
                const float* Hb = H + (size_t)blk * NN * DD + t;
                float u0 = 0.f, ut = 0.f;
                int n = 0;
                for (; n + 3 < i; n += 4) {
                    float h0 = Hb[(size_t)n * DD], h1 = Hb[(size_t)(n + 1) * DD];
                    float h2 = Hb[(size_t)(n + 2) * DD], h3 = Hb[(size_t)(n + 3) * DD];
                    u0 += s_ws[n] * h0 + s_ws[n + 1] * h1 + s_ws[n + 2] * h2 + s_ws[n + 3] * h3;
                    ut += s_w[n] * h0 + s_w[n + 1] * h1 + s_w[n + 2] * h2 + s_w[n + 3] * h3;
                }
                for (; n < i; ++n) {
                    float h = Hb[(size_t)n * DD];
                    u0 += s_ws[n] * h; ut += s_w[n] * h;
                }
                s_red[t] = u0;
                s_red2[t] = ut - u0;
            }
            __syncthreads();
            // pack hi/lo and store ublob (bypass u32 stores)
            {
                u32* ub32 = (u32*)(ublob + (size_t)blk * 2048);
                #pragma unroll
                for (int pp = 0; pp < 2; ++pp) {
                    int w = t + pp * 512;
                    int seg = w >> 8, idx = w & 255;
                    const float* src = (seg < 2) ? s_red : s_red2;
                    float v0 = src[idx * 2], v1 = src[idx * 2 + 1];
                    u16 pa, pb;
                    if (seg & 1) {
                        u16 h0 = f2b(v0), h1 = f2b(v1);
                        pa = f2b(v0 - b2f(h0)); pb = f2b(v1 - b2f(h1));
                    } else {
                        pa = f2b(v0); pb = f2b(v1);
                    }
                    stu32_wt(ub32 + w, (u32)pa | ((u32)pb << 16));
                }
            }
        } else {
            int ub = blk - BB;
            #pragma unroll
            for (int pass = 0; pass < 2; ++pass) {
                int tk = wv + pass * 8;
                if (tk < 12) x_tile(i, i & 1, ub, tk >> 2, tk & 3, featblob, WxB, bi_c, bh_p, bc, lr, lq);
            }
        }
        gbar_light(sync, ++gen, blk);

        // ---- PhB: combined gates (all blocks) + M halves (waves 6,7) ----
        gates_task(ublob, s_wc, s_gb, bc, blk, wv, lr, lq);
        if (wv == 6) m_half(ublob, WrB, bc, blk, 0, lr, lq);
        else if (wv == 7) m_half(ublob, WrB, bc, blk, 1, lr, lq);
        gbar_light(sync, ++gen, blk);
    }

    // ---- final: row 127 ----
    if (blk < BB) {
        float Hv = ew_compute(bc + (size_t)blk * BCS2, feat, blk, NN - 1, t);
        out[(size_t)(blk * NN + NN - 1) * DD + t] = Hv;
    }
}

extern "C" void kernel_launch(void* const* d_in, const int* in_sizes, int n_in,
                              void* d_out, int out_size, void* d_ws, size_t ws_size,
                              hipStream_t stream) {
    (void)in_sizes; (void)n_in; (void)out_size; (void)ws_size;
    const float* feat = (const float*)d_in[0];
    const float* Wi_c = (const float*)d_in[1];
    const float* Wh_c = (const float*)d_in[2];
    const float* bi_c = (const float*)d_in[3];
    const float* bh_c = (const float*)d_in[4];
    const float* Wi_p = (const float*)d_in[5];
    const float* Wh_p = (const float*)d_in[6];
    const float* bi_p = (const float*)d_in[7];
    const float* bh_p = (const float*)d_in[8];
    const float* lin_w = (const float*)d_in[9];
    const float* lin_b = (const float*)d_in[10];
    const float* Wr0 = (const float*)d_in[11];
    const float* Wr1 = (const float*)d_in[12];
    const int* adj = (const int*)d_in[13];
    const int* smask = (const int*)d_in[14];
    float* out = (float*)d_out;

    char* ws = (char*)d_ws;
    size_t off = 0;
    int* sync_ = (int*)(ws + off);      off += 16384;
    float* H = (float*)(ws + off);      off += (size_t)BB * NN * DD * 4;      // 16.8 MB
    float* q = (float*)(ws + off);      off += (size_t)BB * NN * 4;
    u16* ublob = (u16*)(ws + off);      off += (size_t)BB * 2048 * 2;         // 256 KB
    u16* featblob = (u16*)(ws + off);   off += (size_t)BB * NN * 1024 * 2;    // 16.8 MB
    float* bc = (float*)(ws + off);     off += (size_t)BB * BCS2 * 4;         // 2.6 MB
    u16* WrB = (u16*)(ws + off);        off += (size_t)512 * 2048 * 2;        // 2 MB
    u16* WxB = (u16*)(ws + off);        off += (size_t)3072 * 1024 * 2;       // 6.3 MB

    (void)hipMemsetAsync(d_ws, 0, 16384, stream);   // reset barrier flags + epoch
    hipLaunchKernelGGL(grn_kernel, dim3(NBLK), dim3(NTHR), 0, stream,
                       feat, Wi_c, Wh_c, bi_c, bh_c, Wi_p, Wh_p, bi_p, bh_p,
                       lin_w, lin_b, Wr0, Wr1, adj, smask, out,
                       H, q, ublob, featblob, bc, WrB, WxB, sync_);
}

// Round 7
// 6960.102 us; speedup vs baseline: 1.1343x; 1.1343x over previous
//
#include <hip/hip_runtime.h>

#define BB 64
#define NN 128
#define DD 512
#define NBLK 128
#define NTHR 512
#define SGS 209   // s_g row stride (f32): 192 gates + 16 M + 1 pad

typedef unsigned short u16;
typedef unsigned int u32;
typedef unsigned long long u64;
typedef __attribute__((ext_vector_type(8))) __bf16 bf16x8;
typedef __attribute__((ext_vector_type(4))) float f32x4;

#define MFMA16(a,b,c) __builtin_amdgcn_mfma_f32_16x16x32_bf16((a),(b),(c),0,0,0)

__device__ __forceinline__ float b2f(u16 u) {
    union { u32 i; float f; } c; c.i = ((u32)u) << 16; return c.f;
}
__device__ __forceinline__ u16 f2b(float f) {
    union { float f; u32 i; } c; c.f = f;
    return (u16)((c.i + 0x7FFFu + ((c.i >> 16) & 1u)) >> 16);
}
__device__ __forceinline__ float sigm(float x) { return 1.f / (1.f + __expf(-x)); }
__device__ __forceinline__ float tanh_(float x) {
    x = fminf(fmaxf(x, -15.f), 15.f);
    float e = __expf(2.f * x);
    return (e - 1.f) / (e + 1.f);
}

// relaxed agent-scope accessors (coherence-point ops, no wbl2/inv)
__device__ __forceinline__ float at_ldf(float* p) {
    return __hip_atomic_load(p, __ATOMIC_RELAXED, __HIP_MEMORY_SCOPE_AGENT);
}
__device__ __forceinline__ int at_ldi(int* p) {
    return __hip_atomic_load(p, __ATOMIC_RELAXED, __HIP_MEMORY_SCOPE_AGENT);
}
__device__ __forceinline__ void at_stu64(u64* p, u64 v) {
    __hip_atomic_store(p, v, __ATOMIC_RELAXED, __HIP_MEMORY_SCOPE_AGENT);
}
__device__ __forceinline__ void at_addf(float* p, float v) {
    (void)__hip_atomic_fetch_add(p, v, __ATOMIC_RELAXED, __HIP_MEMORY_SCOPE_AGENT);
}
__device__ __forceinline__ void at_addi(int* p, int v) {
    (void)__hip_atomic_fetch_add(p, v, __ATOMIC_RELAXED, __HIP_MEMORY_SCOPE_AGENT);
}

// heavy barrier (acq/rel) — used ONCE after the prologue to publish cached blobs
__device__ __forceinline__ void gbar_heavy(int* sync, int gen, int blk) {
    __syncthreads();
    int* epoch = sync;
    if (blk == 0) {
        const int t = threadIdx.x;
        int done = (t == 0 || t >= NBLK) ? 1 : 0;
        int* myarr = sync + 256 + t * 16;
        int it = 0;
        for (;;) {
            if (!done) {
                int v = ((it & 15) == 15)
                    ? __hip_atomic_load(myarr, __ATOMIC_ACQUIRE, __HIP_MEMORY_SCOPE_AGENT)
                    : __hip_atomic_load(myarr, __ATOMIC_RELAXED, __HIP_MEMORY_SCOPE_AGENT);
                done = (v >= gen);
            }
            ++it;
            if (__syncthreads_and(done)) break;
            __builtin_amdgcn_s_sleep(1);
        }
        if (t == 0) {
            (void)__hip_atomic_load(sync + 256 + 16, __ATOMIC_ACQUIRE, __HIP_MEMORY_SCOPE_AGENT);
            __hip_atomic_store(epoch, gen, __ATOMIC_RELEASE, __HIP_MEMORY_SCOPE_AGENT);
        }
        __syncthreads();
    } else {
        if (threadIdx.x == 0) {
            __hip_atomic_store(sync + 256 + blk * 16, gen, __ATOMIC_RELEASE, __HIP_MEMORY_SCOPE_AGENT);
            int it = 0;
            for (;;) {
                int v = ((it & 15) == 15)
                    ? __hip_atomic_load(epoch, __ATOMIC_ACQUIRE, __HIP_MEMORY_SCOPE_AGENT)
                    : __hip_atomic_load(epoch, __ATOMIC_RELAXED, __HIP_MEMORY_SCOPE_AGENT);
                ++it;
                if (v >= gen) break;
                __builtin_amdgcn_s_sleep(1);
            }
            (void)__hip_atomic_load(epoch, __ATOMIC_ACQUIRE, __HIP_MEMORY_SCOPE_AGENT);
        }
        __syncthreads();
    }
}

// light all-to-all barrier: pure relaxed flags (no wbl2/inv ever)
__device__ __forceinline__ void gbar_lite(int* flags, int gen, int blk) {
    __syncthreads();   // all waves drain vmem before their s_barrier
    if (threadIdx.x == 0)
        __hip_atomic_store(flags + blk * 16, gen, __ATOMIC_RELAXED, __HIP_MEMORY_SCOPE_AGENT);
    if (threadIdx.x < NBLK) {
        while (__hip_atomic_load(flags + threadIdx.x * 16, __ATOMIC_RELAXED, __HIP_MEMORY_SCOPE_AGENT) < gen)
            __builtin_amdgcn_s_sleep(1);
    }
    __syncthreads();
}

// ---- GEMM tile tasks: M=16 (batches), N=16 cols, output into s_g ----
// u-gates tile g (0..5): cols {g<3: g*512+d ; g>=3: 1536+(g-3)*512+d}, K=1024 hi/lo 3-term
__device__ __forceinline__ void wc_tile(
    const u16* __restrict__ ubA, const u16* __restrict__ WcB, float* s_g,
    int g, int d0, int b0, int lr, int lq)
{
    const int colg = (g < 3) ? (g * 512 + d0 + lr) : (1536 + (g - 3) * 512 + d0 + lr);
    const u16* wcol = WcB + (size_t)colg * 2048;
    const u16* ar = ubA + (size_t)(b0 + lr) * 2048;
    f32x4 acc = {0.f, 0.f, 0.f, 0.f};
    #pragma unroll 4
    for (int c = 0; c < 16; ++c) {
        int kk = c * 32 + lq * 8;
        bf16x8 ah = *(const bf16x8*)(ar + kk);
        bf16x8 al = *(const bf16x8*)(ar + 512 + kk);
        bf16x8 wh = *(const bf16x8*)(wcol + kk);
        bf16x8 wl = *(const bf16x8*)(wcol + 1024 + kk);
        acc = MFMA16(ah, wh, acc); acc = MFMA16(al, wh, acc); acc = MFMA16(ah, wl, acc);
    }
    #pragma unroll 4
    for (int c = 0; c < 16; ++c) {
        int kk = c * 32 + lq * 8;
        bf16x8 ah = *(const bf16x8*)(ar + 1024 + kk);
        bf16x8 al = *(const bf16x8*)(ar + 1536 + kk);
        bf16x8 wh = *(const bf16x8*)(wcol + 512 + kk);
        bf16x8 wl = *(const bf16x8*)(wcol + 1536 + kk);
        acc = MFMA16(ah, wh, acc); acc = MFMA16(al, wh, acc); acc = MFMA16(ah, wl, acc);
    }
    #pragma unroll
    for (int r = 0; r < 4; ++r)
        s_g[(lq * 4 + r) * SGS + g * 16 + lr] = acc[r];
}

// x-gates tile g (0..5): A = featblob row j, K=512 hi/lo 3-term
__device__ __forceinline__ void wx_tile(
    int j, const u16* __restrict__ featblob, const u16* __restrict__ WxB, float* s_g,
    int g, int d0, int b0, int lr, int lq)
{
    const int colg = (g < 3) ? (g * 512 + d0 + lr) : (1536 + (g - 3) * 512 + d0 + lr);
    const u16* wcol = WxB + (size_t)colg * 1024;
    const u16* ar = featblob + (size_t)(j * 64 + b0 + lr) * 1024;
    f32x4 acc = {0.f, 0.f, 0.f, 0.f};
    #pragma unroll 4
    for (int c = 0; c < 16; ++c) {
        int kk = c * 32 + lq * 8;
        bf16x8 ah = *(const bf16x8*)(ar + kk);
        bf16x8 al = *(const bf16x8*)(ar + 512 + kk);
        bf16x8 wh = *(const bf16x8*)(wcol + kk);
        bf16x8 wl = *(const bf16x8*)(wcol + 512 + kk);
        acc = MFMA16(ah, wh, acc); acc = MFMA16(al, wh, acc); acc = MFMA16(ah, wl, acc);
    }
    #pragma unroll
    for (int r = 0; r < 4; ++r)
        s_g[(lq * 4 + r) * SGS + 96 + g * 16 + lr] = acc[r];
}

// M tile: cols = d-window, WrB col layout [w0h|w0l|w1h|w1l], M = u0.w0 + u1.w1
__device__ __forceinline__ void m_tile(
    const u16* __restrict__ ubA, const u16* __restrict__ WrB, float* s_g,
    int d0, int b0, int lr, int lq)
{
    const u16* wcol = WrB + (size_t)(d0 + lr) * 2048;
    const u16* ar = ubA + (size_t)(b0 + lr) * 2048;
    f32x4 acc = {0.f, 0.f, 0.f, 0.f};
    #pragma unroll 4
    for (int c = 0; c < 16; ++c) {
        int kk = c * 32 + lq * 8;
        bf16x8 ah = *(const bf16x8*)(ar + kk);
        bf16x8 al = *(const bf16x8*)(ar + 512 + kk);
        bf16x8 wh = *(const bf16x8*)(wcol + kk);
        bf16x8 wl = *(const bf16x8*)(wcol + 512 + kk);
        acc = MFMA16(ah, wh, acc); acc = MFMA16(al, wh, acc); acc = MFMA16(ah, wl, acc);
    }
    #pragma unroll 4
    for (int c = 0; c < 16; ++c) {
        int kk = c * 32 + lq * 8;
        bf16x8 ah = *(const bf16x8*)(ar + 1024 + kk);
        bf16x8 al = *(const bf16x8*)(ar + 1536 + kk);
        bf16x8 wh = *(const bf16x8*)(wcol + 1024 + kk);
        bf16x8 wl = *(const bf16x8*)(wcol + 1536 + kk);
        acc = MFMA16(ah, wh, acc); acc = MFMA16(al, wh, acc); acc = MFMA16(ah, wl, acc);
    }
    #pragma unroll
    for (int r = 0; r < 4; ++r)
        s_g[(lq * 4 + r) * SGS + 192 + lr] = acc[r];
}

__global__ __launch_bounds__(NTHR) void grn_kernel(
    const float* __restrict__ feat, const float* __restrict__ Wi_c, const float* __restrict__ Wh_c,
    const float* __restrict__ bi_c, const float* __restrict__ bh_c,
    const float* __restrict__ Wi_p, const float* __restrict__ Wh_p,
    const float* __restrict__ bi_p, const float* __restrict__ bh_p,
    const float* __restrict__ lin_w, const float* __restrict__ lin_b,
    const float* __restrict__ Wr0, const float* __restrict__ Wr1,
    const int* __restrict__ adj, const int* __restrict__ smask,
    float* __restrict__ out,
    u16* __restrict__ WcB, u16* __restrict__ WxB, u16* __restrict__ WrB,
    u16* __restrict__ featblob, float* __restrict__ H, float* __restrict__ hk,
    int* __restrict__ hkcnt, float* __restrict__ q, u16* __restrict__ ublob,
    int* __restrict__ sync)
{
    const int t = threadIdx.x, blk = blockIdx.x;
    const int lane = t & 63, wv = t >> 6;
    const int lr = lane & 15, lq = lane >> 4;
    const int s = blk & 31, bg = blk >> 5;
    const int d0 = s * 16, b0 = bg * 16;

    __shared__ float s_wgf[DD * 24];          // 48KB, prologue staging
    __shared__ float s_g[16 * SGS];           // gates staging
    __shared__ float s_hk[16 * NN];           // running hk cache
    __shared__ float s_w[16 * NN];
    __shared__ float s_ws[16 * NN];
    __shared__ __align__(16) u16 s_u[16 * 4 * 16];

    int* lflags = sync + 4096;

    // ===================== prologue =====================
    // featblob[(n*64+b)] = feat[b,n,:] as bf16 hi/lo
    for (int rr = 0; rr < 64; ++rr) {
        int gr = blk * 64 + rr;
        int bb_ = gr >> 7, nn_ = gr & 127;
        float x = feat[(size_t)gr * DD + t];
        u16 h = f2b(x);
        u16* dst = featblob + (size_t)(nn_ * 64 + bb_) * 1024;
        dst[t] = h;
        dst[512 + t] = f2b(x - b2f(h));
    }
    // WrB: 512 cols (=d) x [w0h|w0l|w1h|w1l]
    for (int cc = 0; cc < 4; ++cc) {
        int c = blk * 4 + cc;
        float w0 = Wr0[(size_t)c * DD + t], w1 = Wr1[(size_t)c * DD + t];
        u16 h0 = f2b(w0), h1 = f2b(w1);
        u16* dst = WrB + (size_t)c * 2048;
        dst[t] = h0; dst[512 + t] = f2b(w0 - b2f(h0));
        dst[1024 + t] = h1; dst[1536 + t] = f2b(w1 - b2f(h1));
    }
    // WxB: 3072 cols ([Wi_c|Wh_p]) x [h|l]
    for (int cc = 0; cc < 24; ++cc) {
        int c = blk * 24 + cc;
        const float* src = (c < 1536) ? (Wi_c + (size_t)c * DD) : (Wh_p + (size_t)(c - 1536) * DD);
        float w = src[t];
        u16 h = f2b(w);
        WxB[(size_t)c * 1024 + t] = h;
        WxB[(size_t)c * 1024 + 512 + t] = f2b(w - b2f(h));
    }
    // q[b*NN+n] = feat . wq + lin_b
    {
        float linb = lin_b[0];
        float wqf[8];
        #pragma unroll
        for (int jj = 0; jj < 8; ++jj) wqf[jj] = lin_w[lane * 8 + jj];
        for (int rr = 0; rr < 8; ++rr) {
            int row = blk * 64 + wv * 8 + rr;
            const float* fp = feat + (size_t)row * DD + lane * 8;
            float p = 0.f;
            #pragma unroll
            for (int jj = 0; jj < 8; ++jj) p += fp[jj] * wqf[jj];
            #pragma unroll
            for (int off = 32; off; off >>= 1) p += __shfl_down(p, off, 64);
            if (lane == 0) q[row] = p + linb;
        }
    }
    // zero hk (128*64 f32) and hkcnt (128*4*16 int)
    if (t < 64) hk[blk * 64 + t] = 0.f;
    if (t < 64) hkcnt[blk * 64 + t] = 0;
    // WcB: combined weights, 24 cols per block: Wcomb[k, col] = sum_j Wr{0|1}[j,k] * Wg[col,j]
    {
        int jg0 = blk * 24;
        for (int cc = 0; cc < 24; ++cc) {
            int jg = jg0 + cc;
            const float* src = (jg < 1536) ? (Wh_c + (size_t)jg * DD) : (Wi_p + (size_t)(jg - 1536) * DD);
            s_wgf[t * 24 + cc] = src[t];
        }
        __syncthreads();
        float acc0[24], acc1[24];
        #pragma unroll
        for (int cc = 0; cc < 24; ++cc) { acc0[cc] = 0.f; acc1[cc] = 0.f; }
        for (int j = 0; j < DD; ++j) {
            float wr0 = Wr0[(size_t)j * DD + t];
            float wr1 = Wr1[(size_t)j * DD + t];
            const float* g = s_wgf + j * 24;
            #pragma unroll
            for (int cc = 0; cc < 24; ++cc) {
                float gv = g[cc];
                acc0[cc] += wr0 * gv;
                acc1[cc] += wr1 * gv;
            }
        }
        // layout per col: [W0h 512 | W1h 512 | W0l 512 | W1l 512]
        #pragma unroll
        for (int cc = 0; cc < 24; ++cc) {
            u16* dst = WcB + (size_t)(jg0 + cc) * 2048;
            u16 h0 = f2b(acc0[cc]);
            dst[t] = h0;
            dst[1024 + t] = f2b(acc0[cc] - b2f(h0));
            u16 h1 = f2b(acc1[cc]);
            dst[512 + t] = h1;
            dst[1536 + t] = f2b(acc1[cc] - b2f(h1));
        }
    }
    gbar_heavy(sync, 1, blk);

    const float wk_d = lin_w[DD + d0 + (t & 15)];   // for ew threads (t<256)

    // ===================== main loop: phase k does ew(k-1) then softmax/scan(k) =====================
    int liteg = 0;
    for (int k = 1; k < NN; ++k) {
        const int j = k - 1;
        const u16* ubA = ublob + (size_t)(((j * 67) & 127)) * 131072;
        // ---- A-part: GEMMs for row j ----
        if (j == 0) {
            if (wv < 6) wx_tile(0, featblob, WxB, s_g, wv, d0, b0, lr, lq);
        } else {
            int task = wv;
            if (task < 6) wc_tile(ubA, WcB, s_g, task, d0, b0, lr, lq);
            else wx_tile(j, featblob, WxB, s_g, task - 6, d0, b0, lr, lq);
            if (wv < 5) {
                int task2 = 8 + wv;
                if (task2 < 12) wx_tile(j, featblob, WxB, s_g, task2 - 6, d0, b0, lr, lq);
                else m_tile(ubA, WrB, s_g, d0, b0, lr, lq);
            }
        }
        __syncthreads();
        // ---- ew(j) ----
        if (t < 256) {
            int b = t >> 4, dd = t & 15;
            int gb = b0 + b, d = d0 + dd;
            const float* sg = s_g + b * SGS;
            float x  = feat[((size_t)gb * NN + j) * DD + d];
            float ir = sg[96 + dd]      + bi_c[d];
            float iz = sg[96 + 16 + dd] + bi_c[512 + d];
            float in_ = sg[96 + 32 + dd] + bi_c[1024 + d];
            float ghr = sg[96 + 48 + dd] + bh_p[d];
            float ghz = sg[96 + 64 + dd] + bh_p[512 + d];
            float ghn = sg[96 + 80 + dd] + bh_p[1024 + d];
            float hr  = ((j == 0) ? 0.f : sg[dd])        + bh_c[d];
            float hz  = ((j == 0) ? 0.f : sg[16 + dd])   + bh_c[512 + d];
            float hn  = ((j == 0) ? 0.f : sg[32 + dd])   + bh_c[1024 + d];
            float gir = ((j == 0) ? 0.f : sg[48 + dd])   + bi_p[d];
            float giz = ((j == 0) ? 0.f : sg[64 + dd])   + bi_p[512 + d];
            float gin = ((j == 0) ? 0.f : sg[80 + dd])   + bi_p[1024 + d];
            float Mv  = (j == 0) ? 0.f : sg[192 + dd];
            float r_ = sigm(ir + hr), z_ = sigm(iz + hz);
            float C = (1.f - z_) * tanh_(in_ + r_ * hn) + z_ * Mv;
            float r2 = sigm(gir + ghr), z2 = sigm(giz + ghz);
            float P = (1.f - z2) * tanh_(gin + r2 * ghn) + z2 * x;
            float Hv = C + P;
            H[((size_t)gb * NN + j) * DD + d] = Hv;      // private 64B lines, stays in own L2
            out[((size_t)gb * NN + j) * DD + d] = Hv;
            float hkp = Hv * wk_d;
            #pragma unroll
            for (int off = 8; off; off >>= 1) hkp += __shfl_down(hkp, off, 16);
            if (dd == 0) at_addf(hk + j * 64 + gb, hkp);
        }
        __syncthreads();
        if (t == 0) {
            at_addi(hkcnt + (j * 4 + bg) * 16, 1);
            while (at_ldi(hkcnt + (j * 4 + bg) * 16) < 32) __builtin_amdgcn_s_sleep(1);
        }
        __syncthreads();
        // ---- B-part: softmax(k) + scan(k) + publish u(k) ----
        if (t < 16) s_hk[t * NN + j] = at_ldf(hk + j * 64 + b0 + t);
        __syncthreads();
        {
            int b = t >> 5, sl = t & 31;
            int gb = b0 + b;
            float qv = q[(size_t)gb * NN + k];
            const int* ar_ = adj + ((size_t)gb * NN + k) * NN;
            const int* sr_ = smask + ((size_t)gb * NN + k) * NN;
            float a[4];
            #pragma unroll
            for (int u = 0; u < 4; ++u) {
                int n = sl + u * 32;
                a[u] = (n < k && ar_[n] != 0) ? (qv + s_hk[b * NN + n]) : -1e30f;
            }
            float m = fmaxf(fmaxf(a[0], a[1]), fmaxf(a[2], a[3]));
            #pragma unroll
            for (int off = 16; off; off >>= 1) m = fmaxf(m, __shfl_xor(m, off, 32));
            float e[4], ss = 0.f;
            #pragma unroll
            for (int u = 0; u < 4; ++u) {
                e[u] = (a[u] > -1e29f) ? __expf(a[u] - m) : 0.f;
                ss += e[u];
            }
            #pragma unroll
            for (int off = 16; off; off >>= 1) ss += __shfl_xor(ss, off, 32);
            float inv = 1.f / ss;
            #pragma unroll
            for (int u = 0; u < 4; ++u) {
                int n = sl + u * 32;
                float w = e[u] * inv;
                s_w[b * NN + n] = w;
                s_ws[b * NN + n] = w * (float)sr_[n];
            }
        }
        __syncthreads();
        {
            int b = t >> 5, dd = (t >> 1) & 15, h = t & 1;
            const float* Hb = H + ((size_t)(b0 + b) * NN) * DD + d0 + dd;
            float u0 = 0.f, ut = 0.f;
            for (int n = h; n < k; n += 2) {
                float hv = Hb[(size_t)n * DD];
                u0 += s_ws[b * NN + n] * hv;
                ut += s_w[b * NN + n] * hv;
            }
            u0 += __shfl_xor(u0, 1, 64);
            ut += __shfl_xor(ut, 1, 64);
            if (h == 0) {
                float u1 = ut - u0;
                u16 h0 = f2b(u0), h1 = f2b(u1);
                s_u[(b * 4 + 0) * 16 + dd] = h0;
                s_u[(b * 4 + 1) * 16 + dd] = f2b(u0 - b2f(h0));
                s_u[(b * 4 + 2) * 16 + dd] = h1;
                s_u[(b * 4 + 3) * 16 + dd] = f2b(u1 - b2f(h1));
            }
        }
        __syncthreads();
        if (t < 256) {
            int b = t >> 4, seg = (t >> 2) & 3, q4 = t & 3;
            u64 v = *(const u64*)(s_u + (b * 4 + seg) * 16 + q4 * 4);
            u64* slotW = (u64*)(ublob + (size_t)(((k * 67) & 127)) * 131072);
            at_stu64(slotW + ((((size_t)(b0 + b) * 2048) + seg * 512 + d0 + q4 * 4) >> 2), v);
        }
        gbar_lite(lflags, ++liteg, blk);
    }

    // ===================== tail: row 127 =====================
    {
        const int j = NN - 1;
        const u16* ubA = ublob + (size_t)(((j * 67) & 127)) * 131072;
        int task = wv;
        if (task < 6) wc_tile(ubA, WcB, s_g, task, d0, b0, lr, lq);
        else wx_tile(j, featblob, WxB, s_g, task - 6, d0, b0, lr, lq);
        if (wv < 5) {
            int task2 = 8 + wv;
            if (task2 < 12) wx_tile(j, featblob, WxB, s_g, task2 - 6, d0, b0, lr, lq);
            else m_tile(ubA, WrB, s_g, d0, b0, lr, lq);
        }
        __syncthreads();
        if (t < 256) {
            int b = t >> 4, dd = t & 15;
            int gb = b0 + b, d = d0 + dd;
            const float* sg = s_g + b * SGS;
            float x  = feat[((size_t)gb * NN + j) * DD + d];
            float ir = sg[96 + dd]      + bi_c[d];
            float iz = sg[96 + 16 + dd] + bi_c[512 + d];
            float in_ = sg[96 + 32 + dd] + bi_c[1024 + d];
            float ghr = sg[96 + 48 + dd] + bh_p[d];
            float ghz = sg[96 + 64 + dd] + bh_p[512 + d];
            float ghn = sg[96 + 80 + dd] + bh_p[1024 + d];
            float hr  = sg[dd]      + bh_c[d];
            float hz  = sg[16 + dd] + bh_c[512 + d];
            float hn  = sg[32 + dd] + bh_c[1024 + d];
            float gir = sg[48 + dd] + bi_p[d];
            float giz = sg[64 + dd] + bi_p[512 + d];
            float gin = sg[80 + dd] + bi_p[1024 + d];
            float Mv  = sg[192 + dd];
            float r_ = sigm(ir + hr), z_ = sigm(iz + hz);
            float C = (1.f - z_) * tanh_(in_ + r_ * hn) + z_ * Mv;
            float r2 = sigm(gir + ghr), z2 = sigm(giz + ghz);
            float P = (1.f - z2) * tanh_(gin + r2 * ghn) + z2 * x;
            out[((size_t)gb * NN + j) * DD + d] = C + P;
        }
    }
}

extern "C" void kernel_launch(void* const* d_in, const int* in_sizes, int n_in,
                              void* d_out, int out_size, void* d_ws, size_t ws_size,
                              hipStream_t stream) {
    (void)in_sizes; (void)n_in; (void)out_size; (void)ws_size;
    const float* feat = (const float*)d_in[0];
    const float* Wi_c = (const float*)d_in[1];
    const float* Wh_c = (const float*)d_in[2];
    const float* bi_c = (const float*)d_in[3];
    const float* bh_c = (const float*)d_in[4];
    const float* Wi_p = (const float*)d_in[5];
    const float* Wh_p = (const float*)d_in[6];
    const float* bi_p = (const float*)d_in[7];
    const float* bh_p = (const float*)d_in[8];
    const float* lin_w = (const float*)d_in[9];
    const float* lin_b = (const float*)d_in[10];
    const float* Wr0 = (const float*)d_in[11];
    const float* Wr1 = (const float*)d_in[12];
    const int* adj = (const int*)d_in[13];
    const int* smask = (const int*)d_in[14];
    float* out = (float*)d_out;

    char* ws = (char*)d_ws;
    size_t off = 0;
    int* sync_ = (int*)(ws + off);     off += 32768;
    u16* WcB = (u16*)(ws + off);       off += (size_t)3072 * 2048 * 2;   // 12.6 MB
    u16* WxB = (u16*)(ws + off);       off += (size_t)3072 * 1024 * 2;   // 6.3 MB
    u16* WrB = (u16*)(ws + off);       off += (size_t)512 * 2048 * 2;    // 2 MB
    u16* featblob = (u16*)(ws + off);  off += (size_t)8192 * 1024 * 2;   // 16.8 MB
    float* H = (float*)(ws + off);     off += (size_t)BB * NN * DD * 4;  // 16.8 MB
    float* hk = (float*)(ws + off);    off += (size_t)NN * 64 * 4;       // 32 KB
    int* hkcnt = (int*)(ws + off);     off += (size_t)NN * 4 * 16 * 4;   // 32 KB
    float* q = (float*)(ws + off);     off += (size_t)8192 * 4;          // 32 KB
    u16* ublob = (u16*)(ws + off);     off += (size_t)128 * 131072 * 2;  // 32 MB rotated slots

    (void)hipMemsetAsync(d_ws, 0, 32768, stream);   // reset barrier flags/epoch
    hipLaunchKernelGGL(grn_kernel, dim3(NBLK), dim3(NTHR), 0, stream,
                       feat, Wi_c, Wh_c, bi_c, bh_c, Wi_p, Wh_p, bi_p, bh_p,
                       lin_w, lin_b, Wr0, Wr1, adj, smask, out,
                       WcB, WxB, WrB, featblob, H, hk, hkcnt, q, ublob, sync_);
}